// Round 4
// baseline (112.638 us; speedup 1.0000x reference)
//
#include <hip/hip_runtime.h>
#include <hip/hip_bf16.h>

#define T_DIM 4096
#define E_DIM 2048
#define D_DIM 256
#define NT_SPLIT 5

typedef __attribute__((ext_vector_type(4))) float f32x4;
typedef __attribute__((ext_vector_type(8))) short s16x8;

__device__ __forceinline__ unsigned short f2bf(float f) {
  unsigned int u = __float_as_uint(f);
  unsigned int r = (u + 0x7FFFu + ((u >> 16) & 1u)) >> 16;  // RNE
  return (unsigned short)r;
}
__device__ __forceinline__ float bf2f(unsigned short h) {
  return __uint_as_float(((unsigned int)h) << 16);
}

__device__ __forceinline__ f32x4 mfma16(s16x8 a, s16x8 b, f32x4 c) {
  return __builtin_amdgcn_mfma_f32_16x16x32_bf16(a, b, c, 0, 0, 0);
}

__device__ __forceinline__ void gload_lds16(const void* g, void* l) {
  __builtin_amdgcn_global_load_lds((const __attribute__((address_space(1))) void*)g,
                                   (__attribute__((address_space(3))) void*)l, 16, 0, 0);
}

// ---------------- fused fp32 -> bf16 convert (x, Wq, Wk, Wv in one dispatch) --
__global__ __launch_bounds__(256) void cvt_all(const float* __restrict__ x,
                                               const float* __restrict__ wq,
                                               const float* __restrict__ wk,
                                               const float* __restrict__ wv,
                                               unsigned short* __restrict__ xb,
                                               unsigned short* __restrict__ wb) {
  int blk = blockIdx.x;
  const float* src;
  unsigned short* dst;
  int rel;
  if (blk < 4096)      { src = x;  dst = xb;           rel = blk; }
  else if (blk < 4352) { src = wq; dst = wb;           rel = blk - 4096; }
  else if (blk < 4608) { src = wk; dst = wb + 524288;  rel = blk - 4352; }
  else                 { src = wv; dst = wb + 1048576; rel = blk - 4608; }
  int i = rel * 256 + threadIdx.x;
  float4 a = ((const float4*)src)[i * 2];
  float4 b = ((const float4*)src)[i * 2 + 1];
  uint4 o;
  o.x = (unsigned int)f2bf(a.x) | ((unsigned int)f2bf(a.y) << 16);
  o.y = (unsigned int)f2bf(a.z) | ((unsigned int)f2bf(a.w) << 16);
  o.z = (unsigned int)f2bf(b.x) | ((unsigned int)f2bf(b.y) << 16);
  o.w = (unsigned int)f2bf(b.z) | ((unsigned int)f2bf(b.w) << 16);
  ((uint4*)dst)[i] = o;
}

// ---------------- fused QKV projection GEMM (unchanged from round 3) ----------
__global__ __launch_bounds__(256, 3) void qkv_gemm(
    const unsigned short* __restrict__ xb, const unsigned short* __restrict__ wb,
    unsigned short* __restrict__ Qg, unsigned short* __restrict__ Kg,
    unsigned short* __restrict__ Vt) {
  __shared__ __align__(16) unsigned short Al[2][128 * 64];
  __shared__ __align__(16) unsigned short Bl[2][64 * 64];
  int tid = threadIdx.x, wid = tid >> 6, lane = tid & 63;
  int lr = lane & 15, lk = lane >> 4;
  int bi_ = (int)blockIdx.x;
  int xcd = bi_ & 7, kk = bi_ >> 3;
  int mb_ = (kk / 12) * 8 + xcd, nb_ = kk % 12;
  int bm0 = mb_ * 128, bn0 = nb_ * 64;
  int wm = (wid >> 1) * 64, wn = (wid & 1) * 32;

  f32x4 acc[4][2];
#pragma unroll
  for (int m = 0; m < 4; ++m)
#pragma unroll
    for (int n = 0; n < 2; ++n) acc[m][n] = (f32x4){0.f, 0.f, 0.f, 0.f};

#define STAGE_QKV(kt, buf)                                                              \
  {                                                                                     \
    int k0 = (kt)*64;                                                                   \
    _Pragma("unroll") for (int i2 = 0; i2 < 4; ++i2) {                                  \
      int ci = (wid * 4 + i2) * 64 + lane;                                              \
      int row = ci >> 3, cc = ci & 7;                                                   \
      gload_lds16(&xb[(size_t)(bm0 + row) * E_DIM + k0 + ((cc ^ (row & 7)) << 3)],      \
                  &Al[buf][(size_t)(wid * 4 + i2) * 512]);                              \
    }                                                                                   \
    _Pragma("unroll") for (int i2 = 0; i2 < 2; ++i2) {                                  \
      int ci = (wid * 2 + i2) * 64 + lane;                                              \
      int row = ci >> 3, cc = ci & 7;                                                   \
      gload_lds16(&wb[(size_t)(bn0 + row) * E_DIM + k0 + ((cc ^ (row & 7)) << 3)],      \
                  &Bl[buf][(size_t)(wid * 2 + i2) * 512]);                              \
    }                                                                                   \
  }

  STAGE_QKV(0, 0);
  for (int kt = 0; kt < 32; ++kt) {
    int cur = kt & 1;
    __syncthreads();
    if (kt + 1 < 32) STAGE_QKV(kt + 1, cur ^ 1);
    s16x8 af[2][4], bfr[2][2];
#pragma unroll
    for (int c = 0; c < 2; ++c) {
#pragma unroll
      for (int m = 0; m < 4; ++m)
        af[c][m] = *(const s16x8*)&Al[cur][(size_t)(wm + m * 16 + lr) * 64 +
                                           (((c * 4 + lk) ^ (lr & 7)) << 3)];
#pragma unroll
      for (int n = 0; n < 2; ++n)
        bfr[c][n] = *(const s16x8*)&Bl[cur][(size_t)(wn + n * 16 + lr) * 64 +
                                            (((c * 4 + lk) ^ (lr & 7)) << 3)];
    }
#pragma unroll
    for (int c = 0; c < 2; ++c)
#pragma unroll
      for (int m = 0; m < 4; ++m)
#pragma unroll
        for (int n = 0; n < 2; ++n) acc[m][n] = mfma16(af[c][m], bfr[c][n], acc[m][n]);
  }

#pragma unroll
  for (int m = 0; m < 4; ++m) {
    int grow = bm0 + wm + m * 16 + lk * 4;
#pragma unroll
    for (int n = 0; n < 2; ++n) {
      int gcol = bn0 + wn + n * 16 + lr;
      unsigned short h[4];
#pragma unroll
      for (int r = 0; r < 4; ++r) h[r] = f2bf(acc[m][n][r]);
      if (gcol < 256) {
#pragma unroll
        for (int r = 0; r < 4; ++r) Qg[(size_t)(grow + r) * D_DIM + gcol] = h[r];
      } else if (gcol < 512) {
#pragma unroll
        for (int r = 0; r < 4; ++r) Kg[(size_t)(grow + r) * D_DIM + gcol - 256] = h[r];
      } else {
        uint2 w;
        w.x = (unsigned int)h[0] | ((unsigned int)h[1] << 16);
        w.y = (unsigned int)h[2] | ((unsigned int)h[3] << 16);
        *(uint2*)&Vt[(size_t)(gcol - 512) * T_DIM + grow] = w;
      }
    }
  }
#undef STAGE_QKV
}

// ---------------- flash attention: wave = 32q x 32k, all-LDS 2-way-max --------
// q-tile = 128 rows (4 waves x 32 q). 435 blocks, NT_SPLIT=5 kv-tiles max each.
// K LDS: slot(row,gcs) holds gc = gcs^(row&7)  [row-major granules, full 32-col]
// V LDS: slot(d,gs)    holds koct = gs^((d>>1)&3)
__global__ __launch_bounds__(256, 2) void attn_kernel(
    const unsigned short* __restrict__ Qg, const unsigned short* __restrict__ Kg,
    const unsigned short* __restrict__ Vt, unsigned short* __restrict__ Opart,
    float* __restrict__ mpart, float* __restrict__ lpart) {
  __shared__ __align__(16) unsigned short Kl[2][32 * 256];
  __shared__ __align__(16) unsigned short Vl[2][256 * 32];
  __shared__ __align__(16) unsigned short Pl[4][32 * 40];

  int b = blockIdx.x;
  int t = 31, s = 0;
  {
    int acc = 0;
#pragma unroll 1
    for (int k = 1; k <= 32; ++k) {
      int c = (4 * k + 4) / 5;  // ceil(4k/5)
      if (acc + c > b) { t = k - 1; s = b - acc; break; }
      acc += c;
    }
  }
  int nt = 4 * (t + 1) - NT_SPLIT * s;
  if (nt > NT_SPLIT) nt = NT_SPLIT;

  int tid = threadIdx.x, wid = tid >> 6, lane = tid & 63;
  int lr = lane & 15, lk = lane >> 4;
  int q0w = t * 128 + wid * 32;
  unsigned short* pl = &Pl[wid][0];

  s16x8 qf[2][8];
#pragma unroll
  for (int qb = 0; qb < 2; ++qb)
#pragma unroll
    for (int c = 0; c < 8; ++c)
      qf[qb][c] = *(const s16x8*)&Qg[(size_t)(q0w + qb * 16 + lr) * D_DIM + c * 32 + lk * 8];

  float m_run[2] = {-1e30f, -1e30f}, l_run[2] = {0.f, 0.f};
  f32x4 Oa[2][16];
#pragma unroll
  for (int qb = 0; qb < 2; ++qb)
#pragma unroll
    for (int d = 0; d < 16; ++d) Oa[qb][d] = (f32x4){0.f, 0.f, 0.f, 0.f};
  const float scale = 0.0625f;
  int j0 = NT_SPLIT * s;

#define STAGE_KV(j, buf)                                                             \
  {                                                                                  \
    int kv_ = (j)*32;                                                                \
    _Pragma("unroll") for (int i2 = 0; i2 < 4; ++i2) {                               \
      int l = (wid * 4 + i2) * 64 + lane;                                            \
      int row = l >> 5, gcs = l & 31;                                                \
      gload_lds16(&Kg[(size_t)(kv_ + row) * D_DIM + ((gcs ^ (row & 7)) << 3)],       \
                  &Kl[buf][(size_t)(wid * 4 + i2) * 512]);                           \
    }                                                                                \
    _Pragma("unroll") for (int i2 = 0; i2 < 4; ++i2) {                               \
      int l = (wid * 4 + i2) * 64 + lane;                                            \
      int d_ = l >> 2, gs = l & 3;                                                   \
      gload_lds16(&Vt[(size_t)d_ * T_DIM + kv_ + ((gs ^ ((d_ >> 1) & 3)) << 3)],     \
                  &Vl[buf][(size_t)(wid * 4 + i2) * 512]);                           \
    }                                                                                \
  }

  STAGE_KV(j0, 0);
  for (int n = 0; n < nt; ++n) {
    int j = j0 + n, kv = j * 32, cur = n & 1;
    __syncthreads();  // drains this wave's DMA for buf[cur] + block sync
    if (n + 1 < nt) STAGE_KV(j + 1, cur ^ 1);
    const unsigned short* kl = &Kl[cur][0];
    const unsigned short* vl = &Vl[cur][0];

    // ---- QK^T: S^T[key x q], kf shared across both q-frags ----
    f32x4 sa[2][2];
#pragma unroll
    for (int qb = 0; qb < 2; ++qb)
#pragma unroll
      for (int jb = 0; jb < 2; ++jb) sa[qb][jb] = (f32x4){0.f, 0.f, 0.f, 0.f};
    int sw = lr & 7;
#pragma unroll
    for (int jb = 0; jb < 2; ++jb) {
      int rowbase = (jb * 16 + lr) * 32;
#pragma unroll
      for (int c = 0; c < 8; ++c) {
        s16x8 kf = *(const s16x8*)&kl[(size_t)(rowbase + ((c * 4 + lk) ^ sw)) * 8];
        sa[0][jb] = mfma16(kf, qf[0][c], sa[0][jb]);
        sa[1][jb] = mfma16(kf, qf[1][c], sa[1][jb]);
      }
    }

    // ---- scale + mask + online softmax (per q-frag) ----
    bool needmask = (kv + 31 > q0w);
    float alpha_s[2];
#pragma unroll
    for (int qb = 0; qb < 2; ++qb) {
      int myq = q0w + qb * 16 + lr;
      float tmax = -1e30f;
#pragma unroll
      for (int jb = 0; jb < 2; ++jb) {
#pragma unroll
        for (int r = 0; r < 4; ++r) {
          float v = sa[qb][jb][r] * scale;
          if (needmask && (kv + jb * 16 + lk * 4 + r) > myq) v = -1e30f;
          sa[qb][jb][r] = v;
          tmax = fmaxf(tmax, v);
        }
      }
      tmax = fmaxf(tmax, __shfl_xor(tmax, 16));
      tmax = fmaxf(tmax, __shfl_xor(tmax, 32));
      float m_new = fmaxf(fmaxf(m_run[qb], tmax), -1e29f);
      alpha_s[qb] = __expf(m_run[qb] - m_new);
      float psum = 0.f;
#pragma unroll
      for (int jb = 0; jb < 2; ++jb) {
        float p0 = __expf(sa[qb][jb][0] - m_new);
        float p1 = __expf(sa[qb][jb][1] - m_new);
        float p2 = __expf(sa[qb][jb][2] - m_new);
        float p3 = __expf(sa[qb][jb][3] - m_new);
        psum += (p0 + p1) + (p2 + p3);
        uint2 w;
        w.x = (unsigned int)f2bf(p0) | ((unsigned int)f2bf(p1) << 16);
        w.y = (unsigned int)f2bf(p2) | ((unsigned int)f2bf(p3) << 16);
        *(uint2*)&pl[(qb * 16 + lr) * 40 + jb * 16 + lk * 4] = w;
      }
      psum += __shfl_xor(psum, 16);
      psum += __shfl_xor(psum, 32);
      l_run[qb] = l_run[qb] * alpha_s[qb] + psum;
      m_run[qb] = m_new;
    }

    // ---- rescale O (row q = lk*4+r within each q-frag) ----
    float al[2][4];
#pragma unroll
    for (int qb = 0; qb < 2; ++qb)
#pragma unroll
      for (int r = 0; r < 4; ++r) al[qb][r] = __shfl(alpha_s[qb], lk * 4 + r);
#pragma unroll
    for (int qb = 0; qb < 2; ++qb)
#pragma unroll
      for (int d = 0; d < 16; ++d) {
#pragma unroll
        for (int r = 0; r < 4; ++r) Oa[qb][d][r] *= al[qb][r];
      }

    // ---- PV: vf shared across both q-frags ----
    s16x8 pf0 = *(const s16x8*)&pl[lr * 40 + lk * 8];
    s16x8 pf1 = *(const s16x8*)&pl[(16 + lr) * 40 + lk * 8];
    int vsw = lk ^ ((lr >> 1) & 3);
#pragma unroll
    for (int d = 0; d < 16; ++d) {
      s16x8 vf = *(const s16x8*)&vl[(size_t)((d * 16 + lr) * 4 + vsw) * 8];
      Oa[0][d] = mfma16(pf0, vf, Oa[0][d]);
      Oa[1][d] = mfma16(pf1, vf, Oa[1][d]);
    }
  }

  // ---- store partials: Opart[b][256 d][128 q] bf16 ----
#pragma unroll
  for (int d = 0; d < 16; ++d) {
#pragma unroll
    for (int qb = 0; qb < 2; ++qb) {
      unsigned short h[4];
#pragma unroll
      for (int r = 0; r < 4; ++r) h[r] = f2bf(Oa[qb][d][r]);
      uint2 w;
      w.x = (unsigned int)h[0] | ((unsigned int)h[1] << 16);
      w.y = (unsigned int)h[2] | ((unsigned int)h[3] << 16);
      *(uint2*)&Opart[((size_t)b * 256 + d * 16 + lr) * 128 + wid * 32 + qb * 16 + lk * 4] = w;
    }
  }
  if (lk == 0) {
#pragma unroll
    for (int qb = 0; qb < 2; ++qb) {
      mpart[(size_t)b * 128 + wid * 32 + qb * 16 + lr] = m_run[qb];
      lpart[(size_t)b * 128 + wid * 32 + qb * 16 + lr] = l_run[qb];
    }
  }
#undef STAGE_KV
}

// ---------------- merge variable-split partials -> final output ---------------
// grid = 32 q-tiles x 4 d-groups (64 d); block: 128 q-lanes x 2 d-subgroups.
__global__ __launch_bounds__(256) void merge_kernel(const unsigned short* __restrict__ Opart,
                                                    const float* __restrict__ mpart,
                                                    const float* __restrict__ lpart,
                                                    float* __restrict__ out) {
  __shared__ float trans[128 * 65];
  int blk = blockIdx.x;
  int t = blk >> 2, d0 = (blk & 3) * 64, q0 = t * 128;
  int ql = threadIdx.x & 127, dg = threadIdx.x >> 7;
  int base = 0;
#pragma unroll 1
  for (int k = 1; k <= t; ++k) base += (4 * k + 4) / 5;
  int nb = (4 * (t + 1) + 4) / 5;

  float M = -1e30f, den = 0.f;
  for (int p = 0; p < nb; ++p) {
    float mp = mpart[(size_t)(base + p) * 128 + ql];
    float lp = lpart[(size_t)(base + p) * 128 + ql];
    float Mn = fmaxf(M, mp);
    den = den * __expf(M - Mn) + __expf(mp - Mn) * lp;
    M = Mn;
  }
  float inv = 1.0f / den;

  float acc[32];
#pragma unroll
  for (int k = 0; k < 32; ++k) acc[k] = 0.f;
  for (int p = 0; p < nb; ++p) {
    float w = __expf(mpart[(size_t)(base + p) * 128 + ql] - M);
    const unsigned short* op = &Opart[((size_t)(base + p) * 256 + d0 + dg) * 128 + ql];
#pragma unroll
    for (int k = 0; k < 32; ++k) acc[k] += w * bf2f(op[(size_t)(2 * k) * 128]);
  }
#pragma unroll
  for (int k = 0; k < 32; ++k) trans[ql * 65 + dg + 2 * k] = acc[k] * inv;
  __syncthreads();

#pragma unroll
  for (int kk = 0; kk < 32; ++kk) {
    int q = (threadIdx.x >> 6) + 4 * kk;
    int dd = threadIdx.x & 63;
    out[(size_t)(q0 + q) * 256 + d0 + dd] = trans[q * 65 + dd];
  }
}

// ---------------- host launch --------------------------------------------------
extern "C" void kernel_launch(void* const* d_in, const int* in_sizes, int n_in,
                              void* d_out, int out_size, void* d_ws, size_t ws_size,
                              hipStream_t stream) {
  const float* x  = (const float*)d_in[0];
  const float* Wq = (const float*)d_in[1];
  const float* Wk = (const float*)d_in[2];
  const float* Wv = (const float*)d_in[3];

  char* ws = (char*)d_ws;
  // workspace layout (bytes):
  //   xb    [4096][2048] bf16 : 16,777,216   @ 0
  //   wb    [768][2048]  bf16 :  3,145,728   @ 16,777,216
  //   Qg    [4096][256]  bf16 :  2,097,152   @ 19,922,944
  //   Kg    [4096][256]  bf16 :  2,097,152   @ 22,020,096
  //   Vt    [256][4096]  bf16 :  2,097,152   @ 24,117,248
  //   Opart [435][256][128] bf16: 28,508,160 @ 26,214,400
  //   mpart [435][128] f32    :    222,720   @ 54,722,560
  //   lpart [435][128] f32    :    222,720   @ 54,945,280   (total ~55.2 MB)
  unsigned short* xb = (unsigned short*)(ws);
  unsigned short* wb = (unsigned short*)(ws + 16777216);
  unsigned short* Qg = (unsigned short*)(ws + 19922944);
  unsigned short* Kg = (unsigned short*)(ws + 22020096);
  unsigned short* Vt = (unsigned short*)(ws + 24117248);
  unsigned short* Opart = (unsigned short*)(ws + 26214400);
  float* mpart = (float*)(ws + 54722560);
  float* lpart = (float*)(ws + 54945280);

  cvt_all<<<4864, 256, 0, stream>>>(x, Wq, Wk, Wv, xb, wb);
  qkv_gemm<<<384, 256, 0, stream>>>(xb, wb, Qg, Kg, Vt);
  attn_kernel<<<435, 256, 0, stream>>>(Qg, Kg, Vt, Opart, mpart, lpart);
  merge_kernel<<<128, 256, 0, stream>>>(Opart, mpart, lpart, (float*)d_out);
}

// Round 5
// 101.255 us; speedup vs baseline: 1.1124x; 1.1124x over previous
//
#include <hip/hip_runtime.h>
#include <hip/hip_bf16.h>

#define T_DIM 4096
#define E_DIM 2048
#define D_DIM 256
#define NT_SPLIT 5
#define NWORK 435

typedef __attribute__((ext_vector_type(4))) float f32x4;
typedef __attribute__((ext_vector_type(8))) short s16x8;

__device__ __forceinline__ unsigned short f2bf(float f) {
  unsigned int u = __float_as_uint(f);
  unsigned int r = (u + 0x7FFFu + ((u >> 16) & 1u)) >> 16;  // RNE
  return (unsigned short)r;
}
__device__ __forceinline__ float bf2f(unsigned short h) {
  return __uint_as_float(((unsigned int)h) << 16);
}

__device__ __forceinline__ f32x4 mfma16(s16x8 a, s16x8 b, f32x4 c) {
  return __builtin_amdgcn_mfma_f32_16x16x32_bf16(a, b, c, 0, 0, 0);
}

__device__ __forceinline__ void gload_lds16(const void* g, void* l) {
  __builtin_amdgcn_global_load_lds((const __attribute__((address_space(1))) void*)g,
                                   (__attribute__((address_space(3))) void*)l, 16, 0, 0);
}

// first q-tile t that kv-chunk s participates in (nt = 4(t+1)-5s >= 1)
__device__ __forceinline__ int tmin_f(int s) {
  return s ? ((5 * s - 4) / 4 + 1) : 0;
}

// ---------------- fused fp32 -> bf16 convert (x, Wq, Wk, Wv in one dispatch) --
__global__ __launch_bounds__(256) void cvt_all(const float* __restrict__ x,
                                               const float* __restrict__ wq,
                                               const float* __restrict__ wk,
                                               const float* __restrict__ wv,
                                               unsigned short* __restrict__ xb,
                                               unsigned short* __restrict__ wb) {
  int blk = blockIdx.x;
  const float* src;
  unsigned short* dst;
  int rel;
  if (blk < 4096)      { src = x;  dst = xb;           rel = blk; }
  else if (blk < 4352) { src = wq; dst = wb;           rel = blk - 4096; }
  else if (blk < 4608) { src = wk; dst = wb + 524288;  rel = blk - 4352; }
  else                 { src = wv; dst = wb + 1048576; rel = blk - 4608; }
  int i = rel * 256 + threadIdx.x;
  float4 a = ((const float4*)src)[i * 2];
  float4 b = ((const float4*)src)[i * 2 + 1];
  uint4 o;
  o.x = (unsigned int)f2bf(a.x) | ((unsigned int)f2bf(a.y) << 16);
  o.y = (unsigned int)f2bf(a.z) | ((unsigned int)f2bf(a.w) << 16);
  o.z = (unsigned int)f2bf(b.x) | ((unsigned int)f2bf(b.y) << 16);
  o.w = (unsigned int)f2bf(b.z) | ((unsigned int)f2bf(b.w) << 16);
  ((uint4*)dst)[i] = o;
}

// ---------------- fused QKV projection GEMM (counted-vmcnt pipeline) ----------
__global__ __launch_bounds__(256, 3) void qkv_gemm(
    const unsigned short* __restrict__ xb, const unsigned short* __restrict__ wb,
    unsigned short* __restrict__ Qg, unsigned short* __restrict__ Kg,
    unsigned short* __restrict__ Vt) {
  __shared__ __align__(16) unsigned short Al[2][128 * 64];
  __shared__ __align__(16) unsigned short Bl[2][64 * 64];
  int tid = threadIdx.x, wid = tid >> 6, lane = tid & 63;
  int lr = lane & 15, lk = lane >> 4;
  int bi_ = (int)blockIdx.x;
  int xcd = bi_ & 7, kk = bi_ >> 3;
  int mb_ = (kk / 12) * 8 + xcd, nb_ = kk % 12;
  int bm0 = mb_ * 128, bn0 = nb_ * 64;
  int wm = (wid >> 1) * 64, wn = (wid & 1) * 32;

  f32x4 acc[4][2];
#pragma unroll
  for (int m = 0; m < 4; ++m)
#pragma unroll
    for (int n = 0; n < 2; ++n) acc[m][n] = (f32x4){0.f, 0.f, 0.f, 0.f};

#define STAGE_QKV(kt, buf)                                                              \
  {                                                                                     \
    int k0 = (kt)*64;                                                                   \
    _Pragma("unroll") for (int i2 = 0; i2 < 4; ++i2) {                                  \
      int ci = (wid * 4 + i2) * 64 + lane;                                              \
      int row = ci >> 3, cc = ci & 7;                                                   \
      gload_lds16(&xb[(size_t)(bm0 + row) * E_DIM + k0 + ((cc ^ (row & 7)) << 3)],      \
                  &Al[buf][(size_t)(wid * 4 + i2) * 512]);                              \
    }                                                                                   \
    _Pragma("unroll") for (int i2 = 0; i2 < 2; ++i2) {                                  \
      int ci = (wid * 2 + i2) * 64 + lane;                                              \
      int row = ci >> 3, cc = ci & 7;                                                   \
      gload_lds16(&wb[(size_t)(bn0 + row) * E_DIM + k0 + ((cc ^ (row & 7)) << 3)],      \
                  &Bl[buf][(size_t)(wid * 2 + i2) * 512]);                              \
    }                                                                                   \
  }

  STAGE_QKV(0, 0);
  for (int kt = 0; kt < 32; ++kt) {
    int cur = kt & 1;
    __builtin_amdgcn_s_barrier();  // all waves done reading buf[cur^1]
    if (kt + 1 < 32) {
      STAGE_QKV(kt + 1, cur ^ 1);
      asm volatile("s_waitcnt vmcnt(8)" ::: "memory");  // stage(kt) landed; 8 newer in flight
    } else {
      asm volatile("s_waitcnt vmcnt(0)" ::: "memory");
    }
    __builtin_amdgcn_s_barrier();  // stage(kt) visible to all waves
    s16x8 af[2][4], bfr[2][2];
#pragma unroll
    for (int c = 0; c < 2; ++c) {
#pragma unroll
      for (int m = 0; m < 4; ++m)
        af[c][m] = *(const s16x8*)&Al[cur][(size_t)(wm + m * 16 + lr) * 64 +
                                           (((c * 4 + lk) ^ (lr & 7)) << 3)];
#pragma unroll
      for (int n = 0; n < 2; ++n)
        bfr[c][n] = *(const s16x8*)&Bl[cur][(size_t)(wn + n * 16 + lr) * 64 +
                                            (((c * 4 + lk) ^ (lr & 7)) << 3)];
    }
#pragma unroll
    for (int c = 0; c < 2; ++c)
#pragma unroll
      for (int m = 0; m < 4; ++m)
#pragma unroll
        for (int n = 0; n < 2; ++n) acc[m][n] = mfma16(af[c][m], bfr[c][n], acc[m][n]);
  }

#pragma unroll
  for (int m = 0; m < 4; ++m) {
    int grow = bm0 + wm + m * 16 + lk * 4;
#pragma unroll
    for (int n = 0; n < 2; ++n) {
      int gcol = bn0 + wn + n * 16 + lr;
      unsigned short h[4];
#pragma unroll
      for (int r = 0; r < 4; ++r) h[r] = f2bf(acc[m][n][r]);
      if (gcol < 256) {
#pragma unroll
        for (int r = 0; r < 4; ++r) Qg[(size_t)(grow + r) * D_DIM + gcol] = h[r];
      } else if (gcol < 512) {
#pragma unroll
        for (int r = 0; r < 4; ++r) Kg[(size_t)(grow + r) * D_DIM + gcol - 256] = h[r];
      } else {
        uint2 w;
        w.x = (unsigned int)h[0] | ((unsigned int)h[1] << 16);
        w.y = (unsigned int)h[2] | ((unsigned int)h[3] << 16);
        *(uint2*)&Vt[(size_t)(gcol - 512) * T_DIM + grow] = w;
      }
    }
  }
#undef STAGE_QKV
}

// ---------------- flash attention: counted-vmcnt pipeline + XCD s-grouping ----
// Work enumeration is kv-chunk-major (s-major): all blocks on one XCD share the
// same ~320KB K/V slice -> L2-resident. Per work j: q-tile t (128 rows), kv32
// tiles 5s..5s+nt-1. Wave = 32q x 32k.
__global__ __launch_bounds__(256, 2) void attn_kernel(
    const unsigned short* __restrict__ Qg, const unsigned short* __restrict__ Kg,
    const unsigned short* __restrict__ Vt, unsigned short* __restrict__ Opart,
    float* __restrict__ mpart, float* __restrict__ lpart) {
  __shared__ __align__(16) unsigned short Kl[2][32 * 256];
  __shared__ __align__(16) unsigned short Vl[2][256 * 32];
  __shared__ __align__(16) unsigned short Pl[4][32 * 40];

  // bijective XCD remap (NWORK=435, q=54, r=3): consecutive HW bids (same XCD
  // under %8 round-robin) get contiguous work indices j.
  int i = (int)blockIdx.x;
  int c = i & 7, ii = i >> 3;
  int j = (c < 3) ? (c * 55 + ii) : (3 * 55 + (c - 3) * 54 + ii);
  // decode j -> (s, t), s-major
  int s = 0, t = 0;
  {
    int jj = j;
#pragma unroll 1
    for (int ss = 0; ss < 26; ++ss) {
      int tm = tmin_f(ss);
      int cnt = 32 - tm;
      if (jj < cnt) { s = ss; t = tm + jj; break; }
      jj -= cnt;
    }
  }
  int nt = 4 * (t + 1) - NT_SPLIT * s;
  if (nt > NT_SPLIT) nt = NT_SPLIT;

  int tid = threadIdx.x, wid = tid >> 6, lane = tid & 63;
  int lr = lane & 15, lk = lane >> 4;
  int q0w = t * 128 + wid * 32;
  unsigned short* pl = &Pl[wid][0];

  s16x8 qf[2][8];
#pragma unroll
  for (int qb = 0; qb < 2; ++qb)
#pragma unroll
    for (int cc = 0; cc < 8; ++cc)
      qf[qb][cc] = *(const s16x8*)&Qg[(size_t)(q0w + qb * 16 + lr) * D_DIM + cc * 32 + lk * 8];

  float m_run[2] = {-1e30f, -1e30f}, l_run[2] = {0.f, 0.f};
  f32x4 Oa[2][16];
#pragma unroll
  for (int qb = 0; qb < 2; ++qb)
#pragma unroll
    for (int d = 0; d < 16; ++d) Oa[qb][d] = (f32x4){0.f, 0.f, 0.f, 0.f};
  const float scale = 0.0625f;
  int j0 = NT_SPLIT * s;

#define STAGE_KV(jt, buf)                                                            \
  {                                                                                  \
    int kv_ = (jt)*32;                                                               \
    _Pragma("unroll") for (int i2 = 0; i2 < 4; ++i2) {                               \
      int l = (wid * 4 + i2) * 64 + lane;                                            \
      int row = l >> 5, gcs = l & 31;                                                \
      gload_lds16(&Kg[(size_t)(kv_ + row) * D_DIM + ((gcs ^ (row & 7)) << 3)],       \
                  &Kl[buf][(size_t)(wid * 4 + i2) * 512]);                           \
    }                                                                                \
    _Pragma("unroll") for (int i2 = 0; i2 < 4; ++i2) {                               \
      int l = (wid * 4 + i2) * 64 + lane;                                            \
      int d_ = l >> 2, gs = l & 3;                                                   \
      gload_lds16(&Vt[(size_t)d_ * T_DIM + kv_ + ((gs ^ ((d_ >> 1) & 3)) << 3)],     \
                  &Vl[buf][(size_t)(wid * 4 + i2) * 512]);                           \
    }                                                                                \
  }

  STAGE_KV(j0, 0);
  for (int n = 0; n < nt; ++n) {
    int jt = j0 + n, kv = jt * 32, cur = n & 1;
    __builtin_amdgcn_s_barrier();  // all waves done reading buf[cur^1]
    if (n + 1 < nt) {
      STAGE_KV(jt + 1, cur ^ 1);
      asm volatile("s_waitcnt vmcnt(8)" ::: "memory");  // stage(n) landed
    } else {
      asm volatile("s_waitcnt vmcnt(0)" ::: "memory");
    }
    __builtin_amdgcn_s_barrier();  // stage(n) visible block-wide
    const unsigned short* kl = &Kl[cur][0];
    const unsigned short* vl = &Vl[cur][0];

    // ---- QK^T: S^T[key x q], kf shared across both q-frags ----
    f32x4 sa[2][2];
#pragma unroll
    for (int qb = 0; qb < 2; ++qb)
#pragma unroll
      for (int jb = 0; jb < 2; ++jb) sa[qb][jb] = (f32x4){0.f, 0.f, 0.f, 0.f};
    int sw = lr & 7;
#pragma unroll
    for (int jb = 0; jb < 2; ++jb) {
      int rowbase = (jb * 16 + lr) * 32;
#pragma unroll
      for (int cc = 0; cc < 8; ++cc) {
        s16x8 kf = *(const s16x8*)&kl[(size_t)(rowbase + ((cc * 4 + lk) ^ sw)) * 8];
        sa[0][jb] = mfma16(kf, qf[0][cc], sa[0][jb]);
        sa[1][jb] = mfma16(kf, qf[1][cc], sa[1][jb]);
      }
    }

    // ---- scale + mask + online softmax (per q-frag) ----
    bool needmask = (kv + 31 > q0w);
    float alpha_s[2];
#pragma unroll
    for (int qb = 0; qb < 2; ++qb) {
      int myq = q0w + qb * 16 + lr;
      float tmax = -1e30f;
#pragma unroll
      for (int jb = 0; jb < 2; ++jb) {
#pragma unroll
        for (int r = 0; r < 4; ++r) {
          float v = sa[qb][jb][r] * scale;
          if (needmask && (kv + jb * 16 + lk * 4 + r) > myq) v = -1e30f;
          sa[qb][jb][r] = v;
          tmax = fmaxf(tmax, v);
        }
      }
      tmax = fmaxf(tmax, __shfl_xor(tmax, 16));
      tmax = fmaxf(tmax, __shfl_xor(tmax, 32));
      float m_new = fmaxf(fmaxf(m_run[qb], tmax), -1e29f);
      alpha_s[qb] = __expf(m_run[qb] - m_new);
      float psum = 0.f;
#pragma unroll
      for (int jb = 0; jb < 2; ++jb) {
        float p0 = __expf(sa[qb][jb][0] - m_new);
        float p1 = __expf(sa[qb][jb][1] - m_new);
        float p2 = __expf(sa[qb][jb][2] - m_new);
        float p3 = __expf(sa[qb][jb][3] - m_new);
        psum += (p0 + p1) + (p2 + p3);
        uint2 w;
        w.x = (unsigned int)f2bf(p0) | ((unsigned int)f2bf(p1) << 16);
        w.y = (unsigned int)f2bf(p2) | ((unsigned int)f2bf(p3) << 16);
        *(uint2*)&pl[(qb * 16 + lr) * 40 + jb * 16 + lk * 4] = w;
      }
      psum += __shfl_xor(psum, 16);
      psum += __shfl_xor(psum, 32);
      l_run[qb] = l_run[qb] * alpha_s[qb] + psum;
      m_run[qb] = m_new;
    }

    // ---- rescale O ----
    float al[2][4];
#pragma unroll
    for (int qb = 0; qb < 2; ++qb)
#pragma unroll
      for (int r = 0; r < 4; ++r) al[qb][r] = __shfl(alpha_s[qb], lk * 4 + r);
#pragma unroll
    for (int qb = 0; qb < 2; ++qb)
#pragma unroll
      for (int d = 0; d < 16; ++d) {
#pragma unroll
        for (int r = 0; r < 4; ++r) Oa[qb][d][r] *= al[qb][r];
      }

    // ---- PV: vf shared across both q-frags ----
    s16x8 pf0 = *(const s16x8*)&pl[lr * 40 + lk * 8];
    s16x8 pf1 = *(const s16x8*)&pl[(16 + lr) * 40 + lk * 8];
    int vsw = lk ^ ((lr >> 1) & 3);
#pragma unroll
    for (int d = 0; d < 16; ++d) {
      s16x8 vf = *(const s16x8*)&vl[(size_t)((d * 16 + lr) * 4 + vsw) * 8];
      Oa[0][d] = mfma16(pf0, vf, Oa[0][d]);
      Oa[1][d] = mfma16(pf1, vf, Oa[1][d]);
    }
  }

  // ---- store partials: Opart[j][256 d][128 q] bf16 ----
#pragma unroll
  for (int d = 0; d < 16; ++d) {
#pragma unroll
    for (int qb = 0; qb < 2; ++qb) {
      unsigned short h[4];
#pragma unroll
      for (int r = 0; r < 4; ++r) h[r] = f2bf(Oa[qb][d][r]);
      uint2 w;
      w.x = (unsigned int)h[0] | ((unsigned int)h[1] << 16);
      w.y = (unsigned int)h[2] | ((unsigned int)h[3] << 16);
      *(uint2*)&Opart[((size_t)j * 256 + d * 16 + lr) * 128 + wid * 32 + qb * 16 + lk * 4] = w;
    }
  }
  if (lk == 0) {
#pragma unroll
    for (int qb = 0; qb < 2; ++qb) {
      mpart[(size_t)j * 128 + wid * 32 + qb * 16 + lr] = m_run[qb];
      lpart[(size_t)j * 128 + wid * 32 + qb * 16 + lr] = l_run[qb];
    }
  }
#undef STAGE_KV
}

// ---------------- merge partials (s-major indexing), single online pass -------
__global__ __launch_bounds__(256) void merge_kernel(const unsigned short* __restrict__ Opart,
                                                    const float* __restrict__ mpart,
                                                    const float* __restrict__ lpart,
                                                    float* __restrict__ out) {
  __shared__ float trans[128 * 65];
  int blk = blockIdx.x;
  int t = blk >> 2, d0 = (blk & 3) * 64, q0 = t * 128;
  int ql = threadIdx.x & 127, dg = threadIdx.x >> 7;

  float M = -1e30f, den = 0.f;
  float acc[32];
#pragma unroll
  for (int k = 0; k < 32; ++k) acc[k] = 0.f;

  int C = 0;
#pragma unroll 1
  for (int ss = 0; ss < 26; ++ss) {
    int tm = tmin_f(ss);
    int cnt = 32 - tm;
    if (t >= tm && NT_SPLIT * ss < 4 * (t + 1)) {
      int p = C + (t - tm);
      float mp = mpart[(size_t)p * 128 + ql];
      float lp = lpart[(size_t)p * 128 + ql];
      float Mn = fmaxf(M, mp);
      float sc = __expf(M - Mn);
      float w = __expf(mp - Mn);
      den = den * sc + w * lp;
      const unsigned short* op = &Opart[((size_t)p * 256 + d0 + dg) * 128 + ql];
#pragma unroll
      for (int k = 0; k < 32; ++k) acc[k] = acc[k] * sc + w * bf2f(op[(size_t)(2 * k) * 128]);
      M = Mn;
    }
    C += cnt;
  }
  float inv = 1.0f / den;
#pragma unroll
  for (int k = 0; k < 32; ++k) trans[ql * 65 + dg + 2 * k] = acc[k] * inv;
  __syncthreads();

#pragma unroll
  for (int kk = 0; kk < 32; ++kk) {
    int q = (threadIdx.x >> 6) + 4 * kk;
    int dd = threadIdx.x & 63;
    out[(size_t)(q0 + q) * 256 + d0 + dd] = trans[q * 65 + dd];
  }
}

// ---------------- host launch --------------------------------------------------
extern "C" void kernel_launch(void* const* d_in, const int* in_sizes, int n_in,
                              void* d_out, int out_size, void* d_ws, size_t ws_size,
                              hipStream_t stream) {
  const float* x  = (const float*)d_in[0];
  const float* Wq = (const float*)d_in[1];
  const float* Wk = (const float*)d_in[2];
  const float* Wv = (const float*)d_in[3];

  char* ws = (char*)d_ws;
  // workspace layout (bytes):
  //   xb    [4096][2048] bf16 : 16,777,216   @ 0
  //   wb    [768][2048]  bf16 :  3,145,728   @ 16,777,216
  //   Qg    [4096][256]  bf16 :  2,097,152   @ 19,922,944
  //   Kg    [4096][256]  bf16 :  2,097,152   @ 22,020,096
  //   Vt    [256][4096]  bf16 :  2,097,152   @ 24,117,248
  //   Opart [435][256][128] bf16: 28,508,160 @ 26,214,400
  //   mpart [435][128] f32    :    222,720   @ 54,722,560
  //   lpart [435][128] f32    :    222,720   @ 54,945,280   (total ~55.2 MB)
  unsigned short* xb = (unsigned short*)(ws);
  unsigned short* wb = (unsigned short*)(ws + 16777216);
  unsigned short* Qg = (unsigned short*)(ws + 19922944);
  unsigned short* Kg = (unsigned short*)(ws + 22020096);
  unsigned short* Vt = (unsigned short*)(ws + 24117248);
  unsigned short* Opart = (unsigned short*)(ws + 26214400);
  float* mpart = (float*)(ws + 54722560);
  float* lpart = (float*)(ws + 54945280);

  cvt_all<<<4864, 256, 0, stream>>>(x, Wq, Wk, Wv, xb, wb);
  qkv_gemm<<<384, 256, 0, stream>>>(xb, wb, Qg, Kg, Vt);
  attn_kernel<<<NWORK, 256, 0, stream>>>(Qg, Kg, Vt, Opart, mpart, lpart);
  merge_kernel<<<128, 256, 0, stream>>>(Opart, mpart, lpart, (float*)d_out);
}